// Round 1
// baseline (1540.432 us; speedup 1.0000x reference)
//
#include <hip/hip_runtime.h>
#include <hip/hip_bf16.h>

// Shapes: b=2, L=2048, d_model=1024, d_inner=2048, d_state=16, dt_rank=64, d_conv=4
// All inputs/outputs fp32.

#define BM 64
#define BN 64
#define BKK 16

// Generic tiled fp32 GEMM: C[M,N] = A[M,K] @ B[K,N] (row-major, arbitrary ld).
// epi==1: C = softplus(acc + bias[col]).
// Requires M%64==0, K%16==0. N arbitrary (guarded).
__global__ __launch_bounds__(256) void gemm_f32(
    const float* __restrict__ A, const float* __restrict__ B, float* __restrict__ C,
    int M, int N, int K, int lda, int ldb, int ldc,
    const float* __restrict__ bias, int epi)
{
    __shared__ float As[BKK][BM];   // As[k][m]
    __shared__ float Bs[BKK][BN];   // Bs[k][n]
    const int bm = blockIdx.y * BM;
    const int bn = blockIdx.x * BN;
    const int tid = threadIdx.x;
    const int tx = tid & 15;        // 16 col-groups
    const int ty = tid >> 4;        // 16 row-groups
    const int a_row = tid >> 2;           // 0..63
    const int a_col = (tid & 3) * 4;      // 0..12
    const int b_row = tid >> 4;           // 0..15
    const int b_col = (tid & 15) * 4;     // 0..60
    const bool fullN = (bn + BN <= N);

    float acc[4][4] = {};

    for (int k0 = 0; k0 < K; k0 += BKK) {
        // stage A tile (transposed into As[k][m])
        {
            const float* ap = A + (size_t)(bm + a_row) * lda + (k0 + a_col);
            float4 av = *(const float4*)ap;
            As[a_col + 0][a_row] = av.x;
            As[a_col + 1][a_row] = av.y;
            As[a_col + 2][a_row] = av.z;
            As[a_col + 3][a_row] = av.w;
        }
        // stage B tile
        {
            const float* bp = B + (size_t)(k0 + b_row) * ldb + (bn + b_col);
            float4 bv;
            if (fullN) {
                bv = *(const float4*)bp;
            } else {
                bv.x = bv.y = bv.z = bv.w = 0.f;
                int rem = N - (bn + b_col);
                if (rem > 0) bv.x = bp[0];
                if (rem > 1) bv.y = bp[1];
                if (rem > 2) bv.z = bp[2];
                if (rem > 3) bv.w = bp[3];
            }
            Bs[b_row][b_col + 0] = bv.x;
            Bs[b_row][b_col + 1] = bv.y;
            Bs[b_row][b_col + 2] = bv.z;
            Bs[b_row][b_col + 3] = bv.w;
        }
        __syncthreads();
        #pragma unroll
        for (int k = 0; k < BKK; ++k) {
            float a[4], b[4];
            #pragma unroll
            for (int i = 0; i < 4; ++i) a[i] = As[k][ty * 4 + i];
            #pragma unroll
            for (int j = 0; j < 4; ++j) b[j] = Bs[k][tx * 4 + j];
            #pragma unroll
            for (int i = 0; i < 4; ++i)
                #pragma unroll
                for (int j = 0; j < 4; ++j)
                    acc[i][j] = fmaf(a[i], b[j], acc[i][j]);
        }
        __syncthreads();
    }

    #pragma unroll
    for (int i = 0; i < 4; ++i) {
        int r = bm + ty * 4 + i;
        #pragma unroll
        for (int j = 0; j < 4; ++j) {
            int col = bn + tx * 4 + j;
            if (col < N) {
                float v = acc[i][j];
                if (epi == 1) {
                    v += bias[col];
                    v = (v > 20.f) ? v : log1pf(__expf(v));  // softplus
                }
                C[(size_t)r * ldc + col] = v;
            }
        }
    }
}

// Depthwise causal conv (d_conv=4) + bias + silu over xin = xr[..., :2048].
// xr layout: (b*L, 4096). Output xs: (b*L, 2048).
__global__ void conv_silu_k(const float* __restrict__ xr, const float* __restrict__ Wc,
                            const float* __restrict__ bc, float* __restrict__ xs, int total)
{
    for (int idx = blockIdx.x * blockDim.x + threadIdx.x; idx < total;
         idx += gridDim.x * blockDim.x) {
        int d = idx & 2047;
        int l = (idx >> 11) & 2047;
        int b = idx >> 22;
        float acc = bc[d];
        const float* wp = Wc + d * 4;
        #pragma unroll
        for (int k = 0; k < 4; ++k) {
            int ll = l - 3 + k;
            if (ll >= 0)
                acc = fmaf(xr[((size_t)(b * 2048 + ll) << 12) + d], wp[k], acc);
        }
        xs[idx] = acc / (1.f + __expf(-acc));   // silu
    }
}

// Selective scan, fused with y *= silu(res) epilogue.
// 16 lanes per (b,d) channel, one lane per state n. h kept in a register.
// Depth-8 register prefetch of all per-step inputs (only ~1 wave/SIMD, so
// latency must be hidden by ILP).
__global__ __launch_bounds__(256) void scan_fused(
    const float* __restrict__ xs,     // (b*L, 2048)
    const float* __restrict__ delta,  // (b*L, 2048)
    const float* __restrict__ xdbl,   // (b*L, 96); B=cols 64..79, C=cols 80..95
    const float* __restrict__ xr,     // (b*L, 4096); res = cols 2048..4095
    const float* __restrict__ A_log,  // (2048, 16)
    const float* __restrict__ Dp,     // (2048)
    float* __restrict__ y)            // (b*L, 2048) -- may alias `delta` (writes trail reads by PF rows)
{
    const int L = 2048, D = 2048;
    const int tid = threadIdx.x;
    const int c = blockIdx.x * 16 + (tid >> 4);   // global channel 0..4095
    const int n = tid & 15;                       // state index
    const int b = c >> 11;
    const int d = c & 2047;

    const float a = -__expf(A_log[d * 16 + n]);
    const float Dd = Dp[d];
    float h = 0.f;

    const size_t rowBL = (size_t)b * L;
    constexpr int PF = 8;
    float dtb[PF], xtb[PF], Bb[PF], Cb[PF], rb[PF];

    #pragma unroll
    for (int j = 0; j < PF; ++j) {
        size_t row = rowBL + j;
        dtb[j] = delta[row * D + d];
        xtb[j] = xs[row * D + d];
        Bb[j]  = xdbl[row * 96 + 64 + n];
        Cb[j]  = xdbl[row * 96 + 80 + n];
        rb[j]  = xr[(row << 12) + 2048 + d];
    }

    for (int t0 = 0; t0 < L; t0 += PF) {
        #pragma unroll
        for (int j = 0; j < PF; ++j) {
            const int t = t0 + j;
            // consume
            float dtv = dtb[j], xtv = xtb[j], Bn = Bb[j], Cn = Cb[j], rv = rb[j];
            // prefetch t+PF (clamped; tail loads are discarded)
            int tn = t + PF; if (tn > L - 1) tn = L - 1;
            size_t row = rowBL + tn;
            dtb[j] = delta[row * D + d];
            xtb[j] = xs[row * D + d];
            Bb[j]  = xdbl[row * 96 + 64 + n];
            Cb[j]  = xdbl[row * 96 + 80 + n];
            rb[j]  = xr[(row << 12) + 2048 + d];
            // recurrence
            float dA = __expf(dtv * a);
            h = fmaf(dA, h, (dtv * xtv) * Bn);
            float p = h * Cn;
            p += __shfl_xor(p, 1);
            p += __shfl_xor(p, 2);
            p += __shfl_xor(p, 4);
            p += __shfl_xor(p, 8);
            if (n == 0) {
                float yv = p + Dd * xtv;
                float sr = rv / (1.f + __expf(-rv));   // silu(res)
                y[(rowBL + t) * D + d] = yv * sr;
            }
        }
    }
}

extern "C" void kernel_launch(void* const* d_in, const int* in_sizes, int n_in,
                              void* d_out, int out_size, void* d_ws, size_t ws_size,
                              hipStream_t stream) {
    const float* x      = (const float*)d_in[0];
    const float* W_in   = (const float*)d_in[1];
    const float* W_conv = (const float*)d_in[2];
    const float* b_conv = (const float*)d_in[3];
    const float* W_x    = (const float*)d_in[4];
    const float* W_dt   = (const float*)d_in[5];
    const float* b_dt   = (const float*)d_in[6];
    const float* A_log  = (const float*)d_in[7];
    const float* Dp     = (const float*)d_in[8];
    const float* W_out  = (const float*)d_in[9];
    float* out = (float*)d_out;

    float* ws   = (float*)d_ws;
    float* xr   = ws;                   // (4096, 4096) = 16,777,216 floats
    float* xs   = xr + 16777216;        // (4096, 2048) =  8,388,608
    float* xdbl = xs + 8388608;         // (4096, 96)   =    393,216
    float* delta= xdbl + 393216;        // (4096, 2048) =  8,388,608
    float* y    = delta;                // alias: scan writes trail delta reads by PF rows

    dim3 blk(256);

    // 1) xr = x @ W_in          (4096 x 4096 x 1024)
    gemm_f32<<<dim3(64, 64), blk, 0, stream>>>(x, W_in, xr, 4096, 4096, 1024,
                                               1024, 4096, 4096, nullptr, 0);
    // 2) xs = silu(causal_dwconv(xr[:, :2048]) + b_conv)
    conv_silu_k<<<dim3(4096), blk, 0, stream>>>(xr, W_conv, b_conv, xs, 8388608);
    // 3) xdbl = xs @ W_x        (4096 x 96 x 2048)
    gemm_f32<<<dim3(2, 64), blk, 0, stream>>>(xs, W_x, xdbl, 4096, 96, 2048,
                                              2048, 96, 96, nullptr, 0);
    // 4) delta = softplus(xdbl[:, :64] @ W_dt + b_dt)   (4096 x 2048 x 64)
    gemm_f32<<<dim3(32, 64), blk, 0, stream>>>(xdbl, W_dt, delta, 4096, 2048, 64,
                                               96, 2048, 2048, b_dt, 1);
    // 5) selective scan (fused * silu(res)) -> y   [y aliases delta]
    scan_fused<<<dim3(256), blk, 0, stream>>>(xs, delta, xdbl, xr, A_log, Dp, y);
    // 6) out = y @ W_out        (4096 x 1024 x 2048)
    gemm_f32<<<dim3(16, 64), blk, 0, stream>>>(y, W_out, out, 4096, 1024, 2048,
                                               2048, 1024, 1024, nullptr, 0);
}

// Round 2
// 813.633 us; speedup vs baseline: 1.8933x; 1.8933x over previous
//
#include <hip/hip_runtime.h>

// Shapes: b=2, L=2048, d_model=1024, d_inner=2048, d_state=16, dt_rank=64, d_conv=4
// Strategy: bf16x3 MFMA for the two big GEMMs, fp32 tile GEMM for small ones,
// chunked 3-pass parallel selective scan.

typedef unsigned short ushort_t;
using short8 = __attribute__((ext_vector_type(8))) short;
using f32x4  = __attribute__((ext_vector_type(4))) float;
using gptr_t = const __attribute__((address_space(1))) unsigned short*;
using sptr_t = __attribute__((address_space(3))) unsigned short*;

__device__ inline ushort_t f2bf(float v) {
    unsigned u = __float_as_uint(v);
    unsigned r = (u + 0x7fff + ((u >> 16) & 1)) >> 16;   // RNE
    return (ushort_t)r;
}
__device__ inline float bf2f(ushort_t h) { return __uint_as_float(((unsigned)h) << 16); }
__device__ inline void split2(float v, ushort_t& h, ushort_t& l) {
    h = f2bf(v);
    l = f2bf(v - bf2f(h));
}

// ---------------- converters ----------------

// fp32 -> bf16 hi/lo, 4 elems/thread
__global__ void split_plain4(const float* __restrict__ in, ushort_t* __restrict__ h,
                             ushort_t* __restrict__ l, int n4) {
    int i = blockIdx.x * blockDim.x + threadIdx.x;
    if (i >= n4) return;
    float4 v = ((const float4*)in)[i];
    ushort4 hh, ll;
    split2(v.x, hh.x, ll.x); split2(v.y, hh.y, ll.y);
    split2(v.z, hh.z, ll.z); split2(v.w, hh.w, ll.w);
    ((ushort4*)h)[i] = hh;
    ((ushort4*)l)[i] = ll;
}

// W: K x N fp32 (row-major) -> Th/Tl: N x K bf16 (row-major). 32x32 LDS tile.
__global__ __launch_bounds__(256) void split_transpose(
    const float* __restrict__ W, ushort_t* __restrict__ Th, ushort_t* __restrict__ Tl,
    int K, int N) {
    __shared__ float tile[32][33];
    int n0 = blockIdx.x * 32, k0 = blockIdx.y * 32;
    int tx = threadIdx.x & 31, ty = threadIdx.x >> 5;   // ty 0..7
    #pragma unroll
    for (int j = 0; j < 4; ++j) {
        int k = ty + j * 8;
        tile[k][tx] = W[(size_t)(k0 + k) * N + n0 + tx];
    }
    __syncthreads();
    #pragma unroll
    for (int j = 0; j < 4; ++j) {
        int nrow = ty + j * 8;
        float v = tile[tx][nrow];   // = W[k0+tx][n0+nrow]
        ushort_t h, l;
        split2(v, h, l);
        size_t o = (size_t)(n0 + nrow) * K + k0 + tx;
        Th[o] = h; Tl[o] = l;
    }
}

// ---------------- bf16x3 MFMA GEMM ----------------
// C[M,N] = (Ah+Al)[M,K] @ (Bh+Bl)[K,N], B given TRANSPOSED (N x K row-major).
// Drop Al@Bl term. Tile 128x128, BK=32, 4 waves (2x2), each wave 64x64.
__global__ __launch_bounds__(256) void gemm_mfma3(
    const ushort_t* __restrict__ Ah, const ushort_t* __restrict__ Al,
    const ushort_t* __restrict__ Bh, const ushort_t* __restrict__ Bl,
    float* __restrict__ C, int M, int N, int K) {
    __shared__ ushort_t sAh[4096], sAl[4096], sBh[4096], sBl[4096];   // 8KB each
    const int tid  = threadIdx.x;
    const int wid  = tid >> 6;
    const int lane = tid & 63;
    const int bm = blockIdx.y * 128;
    const int bn = blockIdx.x * 128;
    const int wr = wid >> 1, wc = wid & 1;

    f32x4 acc[4][4];
    #pragma unroll
    for (int i = 0; i < 4; ++i)
        #pragma unroll
        for (int j = 0; j < 4; ++j) acc[i][j] = (f32x4){0.f, 0.f, 0.f, 0.f};

    for (int k0 = 0; k0 < K; k0 += 32) {
        #pragma unroll
        for (int issue = 0; issue < 2; ++issue) {
            const int off = wid * 2048 + issue * 1024 + lane * 16;  // byte off in 8KB tile
            const int row = off >> 6;            // 64 B per row (32 ushort)
            const int ce  = (off & 63) >> 1;     // ushort col 0..31
            const size_t ga = (size_t)(bm + row) * K + k0 + ce;
            const size_t gb = (size_t)(bn + row) * K + k0 + ce;
            const int lo = (wid * 2048 + issue * 1024) >> 1;  // ushort index, wave-uniform
            __builtin_amdgcn_global_load_lds((gptr_t)(Ah + ga), (sptr_t)&sAh[lo], 16, 0, 0);
            __builtin_amdgcn_global_load_lds((gptr_t)(Al + ga), (sptr_t)&sAl[lo], 16, 0, 0);
            __builtin_amdgcn_global_load_lds((gptr_t)(Bh + gb), (sptr_t)&sBh[lo], 16, 0, 0);
            __builtin_amdgcn_global_load_lds((gptr_t)(Bl + gb), (sptr_t)&sBl[lo], 16, 0, 0);
        }
        __syncthreads();

        const int fr = lane & 15;
        const int kb = (lane >> 4) * 8;
        short8 ah[4], al[4], bh[4], bl[4];
        #pragma unroll
        for (int i = 0; i < 4; ++i) {
            const int ra = (wr * 64 + i * 16 + fr) * 32 + kb;
            ah[i] = *(const short8*)&sAh[ra];
            al[i] = *(const short8*)&sAl[ra];
            const int rb = (wc * 64 + i * 16 + fr) * 32 + kb;
            bh[i] = *(const short8*)&sBh[rb];
            bl[i] = *(const short8*)&sBl[rb];
        }
        #pragma unroll
        for (int i = 0; i < 4; ++i)
            #pragma unroll
            for (int j = 0; j < 4; ++j) {
                acc[i][j] = __builtin_amdgcn_mfma_f32_16x16x32_bf16(ah[i], bh[j], acc[i][j], 0, 0, 0);
                acc[i][j] = __builtin_amdgcn_mfma_f32_16x16x32_bf16(ah[i], bl[j], acc[i][j], 0, 0, 0);
                acc[i][j] = __builtin_amdgcn_mfma_f32_16x16x32_bf16(al[i], bh[j], acc[i][j], 0, 0, 0);
            }
        __syncthreads();
    }

    // C/D layout: col = lane&15, row = (lane>>4)*4 + reg
    #pragma unroll
    for (int i = 0; i < 4; ++i) {
        int row = bm + wr * 64 + i * 16 + (lane >> 4) * 4;
        #pragma unroll
        for (int j = 0; j < 4; ++j) {
            int col = bn + wc * 64 + j * 16 + (lane & 15);
            float* cp = C + (size_t)row * N + col;
            #pragma unroll
            for (int r = 0; r < 4; ++r) cp[(size_t)r * N] = acc[i][j][r];
        }
    }
}

// ---------------- fp32 tile GEMM (small GEMMs) ----------------
#define BM 64
#define BN 64
#define BKK 16
__global__ __launch_bounds__(256) void gemm_f32(
    const float* __restrict__ A, const float* __restrict__ B, float* __restrict__ C,
    int M, int N, int K, int lda, int ldb, int ldc,
    const float* __restrict__ bias, int epi) {
    __shared__ float As[BKK][BM];
    __shared__ float Bs[BKK][BN];
    const int bm = blockIdx.y * BM;
    const int bn = blockIdx.x * BN;
    const int tid = threadIdx.x;
    const int tx = tid & 15;
    const int ty = tid >> 4;
    const int a_row = tid >> 2;
    const int a_col = (tid & 3) * 4;
    const int b_row = tid >> 4;
    const int b_col = (tid & 15) * 4;
    const bool fullN = (bn + BN <= N);

    float acc[4][4] = {};
    for (int k0 = 0; k0 < K; k0 += BKK) {
        {
            const float* ap = A + (size_t)(bm + a_row) * lda + (k0 + a_col);
            float4 av = *(const float4*)ap;
            As[a_col + 0][a_row] = av.x; As[a_col + 1][a_row] = av.y;
            As[a_col + 2][a_row] = av.z; As[a_col + 3][a_row] = av.w;
        }
        {
            const float* bp = B + (size_t)(k0 + b_row) * ldb + (bn + b_col);
            float4 bv;
            if (fullN) bv = *(const float4*)bp;
            else {
                bv.x = bv.y = bv.z = bv.w = 0.f;
                int rem = N - (bn + b_col);
                if (rem > 0) bv.x = bp[0];
                if (rem > 1) bv.y = bp[1];
                if (rem > 2) bv.z = bp[2];
                if (rem > 3) bv.w = bp[3];
            }
            Bs[b_row][b_col + 0] = bv.x; Bs[b_row][b_col + 1] = bv.y;
            Bs[b_row][b_col + 2] = bv.z; Bs[b_row][b_col + 3] = bv.w;
        }
        __syncthreads();
        #pragma unroll
        for (int k = 0; k < BKK; ++k) {
            float a[4], b[4];
            #pragma unroll
            for (int i = 0; i < 4; ++i) a[i] = As[k][ty * 4 + i];
            #pragma unroll
            for (int j = 0; j < 4; ++j) b[j] = Bs[k][tx * 4 + j];
            #pragma unroll
            for (int i = 0; i < 4; ++i)
                #pragma unroll
                for (int j = 0; j < 4; ++j)
                    acc[i][j] = fmaf(a[i], b[j], acc[i][j]);
        }
        __syncthreads();
    }
    #pragma unroll
    for (int i = 0; i < 4; ++i) {
        int r = bm + ty * 4 + i;
        #pragma unroll
        for (int j = 0; j < 4; ++j) {
            int col = bn + tx * 4 + j;
            if (col < N) {
                float v = acc[i][j];
                if (epi == 1) {
                    v += bias[col];
                    v = (v > 20.f) ? v : log1pf(__expf(v));
                }
                C[(size_t)r * ldc + col] = v;
            }
        }
    }
}

// ---------------- conv + silu ----------------
__global__ void conv_silu_k(const float* __restrict__ xr, const float* __restrict__ Wc,
                            const float* __restrict__ bc, float* __restrict__ xs, int total) {
    for (int idx = blockIdx.x * blockDim.x + threadIdx.x; idx < total;
         idx += gridDim.x * blockDim.x) {
        int d = idx & 2047;
        int l = (idx >> 11) & 2047;
        int b = idx >> 22;
        float acc = bc[d];
        const float* wp = Wc + d * 4;
        #pragma unroll
        for (int k = 0; k < 4; ++k) {
            int ll = l - 3 + k;
            if (ll >= 0)
                acc = fmaf(xr[((size_t)(b * 2048 + ll) << 12) + d], wp[k], acc);
        }
        xs[idx] = acc / (1.f + __expf(-acc));
    }
}

// ---------------- chunked selective scan ----------------
// L=2048 -> NC=16 chunks x CL=128. 16 lanes per (b,d,chunk), one per state n.
// Pass 1: per-chunk carry S (h_end with h0=0) and sum(dt) per chunk.
__global__ __launch_bounds__(256) void scan_p1(
    const float* __restrict__ delta, const float* __restrict__ xs,
    const float* __restrict__ xdbl, const float* __restrict__ A_log,
    float* __restrict__ S, float* __restrict__ sumdt) {
    int tid = threadIdx.x;
    int n = tid & 15;
    int s = blockIdx.x * 16 + (tid >> 4);   // 0..65535
    int chunk = s >> 12;
    int c = s & 4095;
    int b = c >> 11, d = c & 2047;
    float a = -__expf(A_log[d * 16 + n]);
    float h = 0.f, sdt = 0.f;
    size_t row0 = (size_t)b * 2048 + chunk * 128;
    for (int t = 0; t < 128; ++t) {
        size_t row = row0 + t;
        float dt = delta[row * 2048 + d];
        float xv = xs[row * 2048 + d];
        float Bn = xdbl[row * 96 + 64 + n];
        sdt += dt;
        float dA = __expf(dt * a);
        h = fmaf(dA, h, dt * xv * Bn);
    }
    S[((size_t)chunk * 4096 + c) * 16 + n] = h;
    if (n == 0) sumdt[chunk * 4096 + c] = sdt;
}

// Pass 2: cross-chunk scan -> chunk-start states H0.
__global__ __launch_bounds__(256) void scan_p2(
    const float* __restrict__ S, const float* __restrict__ sumdt,
    const float* __restrict__ A_log, float* __restrict__ H0) {
    int idx = blockIdx.x * blockDim.x + threadIdx.x;   // 65536 = (c,n)
    int n = idx & 15;
    int c = (idx >> 4) & 4095;
    int d = c & 2047;
    float a = -__expf(A_log[d * 16 + n]);
    float h = 0.f;
    for (int k = 0; k < 16; ++k) {
        H0[((size_t)k * 4096 + c) * 16 + n] = h;
        float P = __expf(a * sumdt[k * 4096 + c]);
        h = fmaf(P, h, S[((size_t)k * 4096 + c) * 16 + n]);
    }
}

// Pass 3: recompute within chunk from H0, emit y = (sum_n h*C + D*x)*silu(res)
// written directly as bf16 hi/lo (A-operand of the out-GEMM).
__global__ __launch_bounds__(256) void scan_p3(
    const float* __restrict__ delta, const float* __restrict__ xs,
    const float* __restrict__ xdbl, const float* __restrict__ xr,
    const float* __restrict__ A_log, const float* __restrict__ Dp,
    const float* __restrict__ H0,
    ushort_t* __restrict__ yh, ushort_t* __restrict__ yl) {
    int tid = threadIdx.x;
    int n = tid & 15;
    int s = blockIdx.x * 16 + (tid >> 4);
    int chunk = s >> 12;
    int c = s & 4095;
    int b = c >> 11, d = c & 2047;
    float a = -__expf(A_log[d * 16 + n]);
    float Dd = Dp[d];
    float h = H0[((size_t)chunk * 4096 + c) * 16 + n];
    size_t row0 = (size_t)b * 2048 + chunk * 128;
    for (int t = 0; t < 128; ++t) {
        size_t row = row0 + t;
        float dt = delta[row * 2048 + d];
        float xv = xs[row * 2048 + d];
        float Bn = xdbl[row * 96 + 64 + n];
        float Cn = xdbl[row * 96 + 80 + n];
        float dA = __expf(dt * a);
        h = fmaf(dA, h, dt * xv * Bn);
        float p = h * Cn;
        p += __shfl_xor(p, 1);
        p += __shfl_xor(p, 2);
        p += __shfl_xor(p, 4);
        p += __shfl_xor(p, 8);
        if (n == 0) {
            float rv = xr[(row << 12) + 2048 + d];
            float yv = fmaf(Dd, xv, p) * (rv / (1.f + __expf(-rv)));
            ushort_t hb, lb;
            split2(yv, hb, lb);
            size_t o = row * 2048 + d;
            yh[o] = hb; yl[o] = lb;
        }
    }
}

// ---------------- launch ----------------
extern "C" void kernel_launch(void* const* d_in, const int* in_sizes, int n_in,
                              void* d_out, int out_size, void* d_ws, size_t ws_size,
                              hipStream_t stream) {
    const float* x      = (const float*)d_in[0];
    const float* W_in   = (const float*)d_in[1];
    const float* W_conv = (const float*)d_in[2];
    const float* b_conv = (const float*)d_in[3];
    const float* W_x    = (const float*)d_in[4];
    const float* W_dt   = (const float*)d_in[5];
    const float* b_dt   = (const float*)d_in[6];
    const float* A_log  = (const float*)d_in[7];
    const float* Dp     = (const float*)d_in[8];
    const float* W_out  = (const float*)d_in[9];
    float* out = (float*)d_out;

    float* ws    = (float*)d_ws;
    float* xr    = ws;                      // 16,777,216 f (64MB)
    float* xs    = xr + 16777216;           //  8,388,608 f (32MB)
    float* xdbl  = xs + 8388608;            //    393,216 f
    float* delta = xdbl + 393216;           //  8,388,608 f (32MB)
    float* S     = delta + 8388608;         //  1,048,576 f (4MB)
    float* H0    = S + 1048576;             //  1,048,576 f (4MB)
    float* sumdt = H0 + 1048576;            //     65,536 f
    ushort_t* base = (ushort_t*)(sumdt + 65536);   // shared bf16 region (40MB)
    // phase A (in-GEMM): xh, xl (4096x1024), WinT h/l (4096x1024)
    ushort_t* xh = base, *xl = base + 4194304;
    ushort_t* winh = base + 8388608, *winl = base + 12582912;
    // phase B (out-GEMM): yh/yl (4096x2048) overlap xh..winl (dead by then);
    // WoutT h/l (1024x2048) placed after, non-overlapping.
    ushort_t* yh = base, *yl = base + 8388608;
    ushort_t* wouth = base + 16777216, *woutl = base + 18874368;

    dim3 blk(256);

    // converters
    split_plain4<<<dim3(4096), blk, 0, stream>>>(x, xh, xl, 1048576);           // 4096x1024
    split_transpose<<<dim3(128, 32), blk, 0, stream>>>(W_in, winh, winl, 1024, 4096);
    split_transpose<<<dim3(32, 64), blk, 0, stream>>>(W_out, wouth, woutl, 2048, 1024);

    // 1) xr = x @ W_in   (4096 x 4096 x 1024), bf16x3 MFMA
    gemm_mfma3<<<dim3(32, 32), blk, 0, stream>>>(xh, xl, winh, winl, xr, 4096, 4096, 1024);
    // 2) xs = silu(causal_dwconv(xr[:, :2048]) + b_conv)
    conv_silu_k<<<dim3(4096), blk, 0, stream>>>(xr, W_conv, b_conv, xs, 8388608);
    // 3) xdbl = xs @ W_x  (4096 x 96 x 2048)
    gemm_f32<<<dim3(2, 64), blk, 0, stream>>>(xs, W_x, xdbl, 4096, 96, 2048,
                                              2048, 96, 96, nullptr, 0);
    // 4) delta = softplus(xdbl[:, :64] @ W_dt + b_dt)  (4096 x 2048 x 64)
    gemm_f32<<<dim3(32, 64), blk, 0, stream>>>(xdbl, W_dt, delta, 4096, 2048, 64,
                                               96, 2048, 2048, b_dt, 1);
    // 5) chunked scan
    scan_p1<<<dim3(4096), blk, 0, stream>>>(delta, xs, xdbl, A_log, S, sumdt);
    scan_p2<<<dim3(256), blk, 0, stream>>>(S, sumdt, A_log, H0);
    scan_p3<<<dim3(4096), blk, 0, stream>>>(delta, xs, xdbl, xr, A_log, Dp, H0, yh, yl);
    // 6) out = y @ W_out  (4096 x 1024 x 2048), bf16x3 MFMA
    gemm_mfma3<<<dim3(8, 32), blk, 0, stream>>>(yh, yl, wouth, woutl, out, 4096, 1024, 2048);
}

// Round 3
// 676.670 us; speedup vs baseline: 2.2765x; 1.2024x over previous
//
#include <hip/hip_runtime.h>

// Shapes: b=2, L=2048, d_model=1024, d_inner=2048, d_state=16, dt_rank=64, d_conv=4
// bf16x3 MFMA for the two big GEMMs; fp32 tile GEMM for small ones;
// chunked 3-pass selective scan with n-in-registers (no cross-lane ops).

typedef unsigned short ushort_t;
using short8 = __attribute__((ext_vector_type(8))) short;
using f32x4  = __attribute__((ext_vector_type(4))) float;
using gptr_t = const __attribute__((address_space(1))) unsigned short*;
using sptr_t = __attribute__((address_space(3))) unsigned short*;

#define NC 64   // chunks
#define CL 32   // chunk length  (NC*CL == 2048)

__device__ inline ushort_t f2bf(float v) {
    unsigned u = __float_as_uint(v);
    unsigned r = (u + 0x7fff + ((u >> 16) & 1)) >> 16;   // RNE
    return (ushort_t)r;
}
__device__ inline float bf2f(ushort_t h) { return __uint_as_float(((unsigned)h) << 16); }
__device__ inline void split2(float v, ushort_t& h, ushort_t& l) {
    h = f2bf(v);
    l = f2bf(v - bf2f(h));
}

// ---------------- converters ----------------

__global__ void split_plain4(const float* __restrict__ in, ushort_t* __restrict__ h,
                             ushort_t* __restrict__ l, int n4) {
    int i = blockIdx.x * blockDim.x + threadIdx.x;
    if (i >= n4) return;
    float4 v = ((const float4*)in)[i];
    ushort4 hh, ll;
    split2(v.x, hh.x, ll.x); split2(v.y, hh.y, ll.y);
    split2(v.z, hh.z, ll.z); split2(v.w, hh.w, ll.w);
    ((ushort4*)h)[i] = hh;
    ((ushort4*)l)[i] = ll;
}

// W: K x N fp32 -> Th/Tl: N x K bf16 (row-major)
__global__ __launch_bounds__(256) void split_transpose(
    const float* __restrict__ W, ushort_t* __restrict__ Th, ushort_t* __restrict__ Tl,
    int K, int N) {
    __shared__ float tile[32][33];
    int n0 = blockIdx.x * 32, k0 = blockIdx.y * 32;
    int tx = threadIdx.x & 31, ty = threadIdx.x >> 5;
    #pragma unroll
    for (int j = 0; j < 4; ++j) {
        int k = ty + j * 8;
        tile[k][tx] = W[(size_t)(k0 + k) * N + n0 + tx];
    }
    __syncthreads();
    #pragma unroll
    for (int j = 0; j < 4; ++j) {
        int nrow = ty + j * 8;
        float v = tile[tx][nrow];
        ushort_t h, l;
        split2(v, h, l);
        size_t o = (size_t)(n0 + nrow) * K + k0 + tx;
        Th[o] = h; Tl[o] = l;
    }
}

// ---------------- bf16x3 MFMA GEMM ----------------
// C[M,N] = (Ah+Al)[M,K] @ (Bh+Bl)[K,N], B TRANSPOSED (N x K). Drop Al@Bl.
// Tile 128x128, BK=32, 4 waves (2x2), each wave 64x64.
__global__ __launch_bounds__(256) void gemm_mfma3(
    const ushort_t* __restrict__ Ah, const ushort_t* __restrict__ Al,
    const ushort_t* __restrict__ Bh, const ushort_t* __restrict__ Bl,
    float* __restrict__ C, int M, int N, int K) {
    __shared__ ushort_t sAh[4096], sAl[4096], sBh[4096], sBl[4096];
    const int tid  = threadIdx.x;
    const int wid  = tid >> 6;
    const int lane = tid & 63;
    const int bm = blockIdx.y * 128;
    const int bn = blockIdx.x * 128;
    const int wr = wid >> 1, wc = wid & 1;

    f32x4 acc[4][4];
    #pragma unroll
    for (int i = 0; i < 4; ++i)
        #pragma unroll
        for (int j = 0; j < 4; ++j) acc[i][j] = (f32x4){0.f, 0.f, 0.f, 0.f};

    for (int k0 = 0; k0 < K; k0 += 32) {
        #pragma unroll
        for (int issue = 0; issue < 2; ++issue) {
            const int off = wid * 2048 + issue * 1024 + lane * 16;
            const int row = off >> 6;
            const int ce  = (off & 63) >> 1;
            const size_t ga = (size_t)(bm + row) * K + k0 + ce;
            const size_t gb = (size_t)(bn + row) * K + k0 + ce;
            const int lo = (wid * 2048 + issue * 1024) >> 1;
            __builtin_amdgcn_global_load_lds((gptr_t)(Ah + ga), (sptr_t)&sAh[lo], 16, 0, 0);
            __builtin_amdgcn_global_load_lds((gptr_t)(Al + ga), (sptr_t)&sAl[lo], 16, 0, 0);
            __builtin_amdgcn_global_load_lds((gptr_t)(Bh + gb), (sptr_t)&sBh[lo], 16, 0, 0);
            __builtin_amdgcn_global_load_lds((gptr_t)(Bl + gb), (sptr_t)&sBl[lo], 16, 0, 0);
        }
        __syncthreads();

        const int fr = lane & 15;
        const int kb = (lane >> 4) * 8;
        short8 ah[4], al[4], bh[4], bl[4];
        #pragma unroll
        for (int i = 0; i < 4; ++i) {
            const int ra = (wr * 64 + i * 16 + fr) * 32 + kb;
            ah[i] = *(const short8*)&sAh[ra];
            al[i] = *(const short8*)&sAl[ra];
            const int rb = (wc * 64 + i * 16 + fr) * 32 + kb;
            bh[i] = *(const short8*)&sBh[rb];
            bl[i] = *(const short8*)&sBl[rb];
        }
        #pragma unroll
        for (int i = 0; i < 4; ++i)
            #pragma unroll
            for (int j = 0; j < 4; ++j) {
                acc[i][j] = __builtin_amdgcn_mfma_f32_16x16x32_bf16(ah[i], bh[j], acc[i][j], 0, 0, 0);
                acc[i][j] = __builtin_amdgcn_mfma_f32_16x16x32_bf16(ah[i], bl[j], acc[i][j], 0, 0, 0);
                acc[i][j] = __builtin_amdgcn_mfma_f32_16x16x32_bf16(al[i], bh[j], acc[i][j], 0, 0, 0);
            }
        __syncthreads();
    }

    #pragma unroll
    for (int i = 0; i < 4; ++i) {
        int row = bm + wr * 64 + i * 16 + (lane >> 4) * 4;
        #pragma unroll
        for (int j = 0; j < 4; ++j) {
            int col = bn + wc * 64 + j * 16 + (lane & 15);
            float* cp = C + (size_t)row * N + col;
            #pragma unroll
            for (int r = 0; r < 4; ++r) cp[(size_t)r * N] = acc[i][j][r];
        }
    }
}

// ---------------- fp32 tile GEMM (small GEMMs) ----------------
#define BM 64
#define BN 64
#define BKK 16
__global__ __launch_bounds__(256) void gemm_f32(
    const float* __restrict__ A, const float* __restrict__ B, float* __restrict__ C,
    int M, int N, int K, int lda, int ldb, int ldc,
    const float* __restrict__ bias, int epi) {
    __shared__ float As[BKK][BM];
    __shared__ float Bs[BKK][BN];
    const int bm = blockIdx.y * BM;
    const int bn = blockIdx.x * BN;
    const int tid = threadIdx.x;
    const int tx = tid & 15;
    const int ty = tid >> 4;
    const int a_row = tid >> 2;
    const int a_col = (tid & 3) * 4;
    const int b_row = tid >> 4;
    const int b_col = (tid & 15) * 4;
    const bool fullN = (bn + BN <= N);

    float acc[4][4] = {};
    for (int k0 = 0; k0 < K; k0 += BKK) {
        {
            const float* ap = A + (size_t)(bm + a_row) * lda + (k0 + a_col);
            float4 av = *(const float4*)ap;
            As[a_col + 0][a_row] = av.x; As[a_col + 1][a_row] = av.y;
            As[a_col + 2][a_row] = av.z; As[a_col + 3][a_row] = av.w;
        }
        {
            const float* bp = B + (size_t)(k0 + b_row) * ldb + (bn + b_col);
            float4 bv;
            if (fullN) bv = *(const float4*)bp;
            else {
                bv.x = bv.y = bv.z = bv.w = 0.f;
                int rem = N - (bn + b_col);
                if (rem > 0) bv.x = bp[0];
                if (rem > 1) bv.y = bp[1];
                if (rem > 2) bv.z = bp[2];
                if (rem > 3) bv.w = bp[3];
            }
            Bs[b_row][b_col + 0] = bv.x; Bs[b_row][b_col + 1] = bv.y;
            Bs[b_row][b_col + 2] = bv.z; Bs[b_row][b_col + 3] = bv.w;
        }
        __syncthreads();
        #pragma unroll
        for (int k = 0; k < BKK; ++k) {
            float a[4], b[4];
            #pragma unroll
            for (int i = 0; i < 4; ++i) a[i] = As[k][ty * 4 + i];
            #pragma unroll
            for (int j = 0; j < 4; ++j) b[j] = Bs[k][tx * 4 + j];
            #pragma unroll
            for (int i = 0; i < 4; ++i)
                #pragma unroll
                for (int j = 0; j < 4; ++j)
                    acc[i][j] = fmaf(a[i], b[j], acc[i][j]);
        }
        __syncthreads();
    }
    #pragma unroll
    for (int i = 0; i < 4; ++i) {
        int r = bm + ty * 4 + i;
        #pragma unroll
        for (int j = 0; j < 4; ++j) {
            int col = bn + tx * 4 + j;
            if (col < N) {
                float v = acc[i][j];
                if (epi == 1) {
                    v += bias[col];
                    v = (v > 20.f) ? v : log1pf(__expf(v));
                }
                C[(size_t)r * ldc + col] = v;
            }
        }
    }
}

// ---------------- conv + silu ----------------
__global__ void conv_silu_k(const float* __restrict__ xr, const float* __restrict__ Wc,
                            const float* __restrict__ bc, float* __restrict__ xs, int total) {
    for (int idx = blockIdx.x * blockDim.x + threadIdx.x; idx < total;
         idx += gridDim.x * blockDim.x) {
        int d = idx & 2047;
        int l = (idx >> 11) & 2047;
        int b = idx >> 22;
        float acc = bc[d];
        const float* wp = Wc + d * 4;
        #pragma unroll
        for (int k = 0; k < 4; ++k) {
            int ll = l - 3 + k;
            if (ll >= 0)
                acc = fmaf(xr[((size_t)(b * 2048 + ll) << 12) + d], wp[k], acc);
        }
        xs[idx] = acc / (1.f + __expf(-acc));
    }
}

// ---------------- chunked selective scan, n in registers ----------------
// Unit u = (chunk, c) with c = (b,d). One LANE per unit, h[16] in registers.
// All 256 lanes of a block share (b, chunk) -> B/C row loads broadcast in L1.

// Pass 1: per-chunk carry S[chunk][c][0..15] (h with h0=0) + sum(dt).
__global__ __launch_bounds__(256) void scan_p1(
    const float* __restrict__ delta, const float* __restrict__ xs,
    const float* __restrict__ xdbl, const float* __restrict__ A_log,
    float* __restrict__ S, float* __restrict__ sumdt) {
    const int u = blockIdx.x * 256 + threadIdx.x;   // 4096*NC units
    const int chunk = u >> 12;
    const int c = u & 4095;
    const int b = c >> 11, d = c & 2047;

    float a[16];
    #pragma unroll
    for (int i = 0; i < 4; ++i) {
        float4 v = ((const float4*)(A_log + d * 16))[i];
        a[4 * i + 0] = -__expf(v.x); a[4 * i + 1] = -__expf(v.y);
        a[4 * i + 2] = -__expf(v.z); a[4 * i + 3] = -__expf(v.w);
    }
    float h[16];
    #pragma unroll
    for (int n = 0; n < 16; ++n) h[n] = 0.f;
    float sdt = 0.f;

    const size_t row0 = (size_t)b * 2048 + (size_t)chunk * CL;
    const float4* xd4 = (const float4*)xdbl;
    #pragma unroll 2
    for (int t = 0; t < CL; ++t) {
        const size_t row = row0 + t;
        float dt = delta[row * 2048 + d];
        float xv = xs[row * 2048 + d];
        float4 Bv[4];
        #pragma unroll
        for (int i = 0; i < 4; ++i) Bv[i] = xd4[row * 24 + 16 + i];
        const float* Bf = (const float*)Bv;
        sdt += dt;
        float du = dt * xv;
        #pragma unroll
        for (int n = 0; n < 16; ++n) {
            float dA = __expf(dt * a[n]);
            h[n] = fmaf(dA, h[n], du * Bf[n]);
        }
    }
    float4* S4 = (float4*)(S + ((size_t)chunk * 4096 + c) * 16);
    #pragma unroll
    for (int i = 0; i < 4; ++i)
        S4[i] = make_float4(h[4 * i + 0], h[4 * i + 1], h[4 * i + 2], h[4 * i + 3]);
    sumdt[chunk * 4096 + c] = sdt;
}

// Pass 2: cross-chunk scan, IN-PLACE: S[k] becomes H0[k] (chunk-start state).
__global__ __launch_bounds__(256) void scan_p2(
    float* __restrict__ S, const float* __restrict__ sumdt,
    const float* __restrict__ A_log) {
    const int idx = blockIdx.x * blockDim.x + threadIdx.x;   // 65536 = (c,n)
    const int n = idx & 15;
    const int c = (idx >> 4) & 4095;
    const int d = c & 2047;
    const float a = -__expf(A_log[d * 16 + n]);
    float h = 0.f;
    for (int k = 0; k < NC; ++k) {
        const size_t o = ((size_t)k * 4096 + c) * 16 + n;
        float carry = S[o];
        S[o] = h;                                   // H0 for chunk k
        float P = __expf(a * sumdt[k * 4096 + c]);
        h = fmaf(P, h, carry);
    }
}

// Pass 3: recompute within chunk from H0 (=S), emit y=(sum_n h*C + D*x)*silu(res)
// as bf16 hi/lo.
__global__ __launch_bounds__(256) void scan_p3(
    const float* __restrict__ delta, const float* __restrict__ xs,
    const float* __restrict__ xdbl, const float* __restrict__ xr,
    const float* __restrict__ A_log, const float* __restrict__ Dp,
    const float* __restrict__ H0,
    ushort_t* __restrict__ yh, ushort_t* __restrict__ yl) {
    const int u = blockIdx.x * 256 + threadIdx.x;
    const int chunk = u >> 12;
    const int c = u & 4095;
    const int b = c >> 11, d = c & 2047;

    float a[16];
    #pragma unroll
    for (int i = 0; i < 4; ++i) {
        float4 v = ((const float4*)(A_log + d * 16))[i];
        a[4 * i + 0] = -__expf(v.x); a[4 * i + 1] = -__expf(v.y);
        a[4 * i + 2] = -__expf(v.z); a[4 * i + 3] = -__expf(v.w);
    }
    float h[16];
    const float4* H4 = (const float4*)(H0 + ((size_t)chunk * 4096 + c) * 16);
    #pragma unroll
    for (int i = 0; i < 4; ++i) {
        float4 v = H4[i];
        h[4 * i + 0] = v.x; h[4 * i + 1] = v.y; h[4 * i + 2] = v.z; h[4 * i + 3] = v.w;
    }
    const float Dd = Dp[d];

    const size_t row0 = (size_t)b * 2048 + (size_t)chunk * CL;
    const float4* xd4 = (const float4*)xdbl;
    #pragma unroll 2
    for (int t = 0; t < CL; ++t) {
        const size_t row = row0 + t;
        float dt = delta[row * 2048 + d];
        float xv = xs[row * 2048 + d];
        float4 BC[8];
        #pragma unroll
        for (int i = 0; i < 8; ++i) BC[i] = xd4[row * 24 + 16 + i];   // B then C
        const float* Bf = (const float*)BC;
        const float* Cf = Bf + 16;
        float du = dt * xv;
        float acc = 0.f;
        #pragma unroll
        for (int n = 0; n < 16; ++n) {
            float dA = __expf(dt * a[n]);
            h[n] = fmaf(dA, h[n], du * Bf[n]);
            acc = fmaf(h[n], Cf[n], acc);
        }
        float rv = xr[(row << 12) + 2048 + d];
        float yv = fmaf(Dd, xv, acc) * (rv / (1.f + __expf(-rv)));
        ushort_t hb, lb;
        split2(yv, hb, lb);
        yh[row * 2048 + d] = hb;
        yl[row * 2048 + d] = lb;
    }
}

// ---------------- launch ----------------
extern "C" void kernel_launch(void* const* d_in, const int* in_sizes, int n_in,
                              void* d_out, int out_size, void* d_ws, size_t ws_size,
                              hipStream_t stream) {
    const float* x      = (const float*)d_in[0];
    const float* W_in   = (const float*)d_in[1];
    const float* W_conv = (const float*)d_in[2];
    const float* b_conv = (const float*)d_in[3];
    const float* W_x    = (const float*)d_in[4];
    const float* W_dt   = (const float*)d_in[5];
    const float* b_dt   = (const float*)d_in[6];
    const float* A_log  = (const float*)d_in[7];
    const float* Dp     = (const float*)d_in[8];
    const float* W_out  = (const float*)d_in[9];
    float* out = (float*)d_out;

    float* ws    = (float*)d_ws;
    float* xr    = ws;                      // 16,777,216 f
    float* xs    = xr + 16777216;           //  8,388,608 f
    float* xdbl  = xs + 8388608;            //    393,216 f
    float* delta = xdbl + 393216;           //  8,388,608 f
    float* S     = delta + 8388608;         //  4,194,304 f (NC*4096*16)
    float* sumdt = S + 4194304;             //    262,144 f
    ushort_t* base = (ushort_t*)(sumdt + 262144);
    // phase A (in-GEMM): xh/xl (4096x1024), WinT h/l (4096x1024)
    ushort_t* xh = base, *xl = base + 4194304;
    ushort_t* winh = base + 8388608, *winl = base + 12582912;
    // phase B (out-GEMM): yh/yl (4096x2048) overlap phase A; WoutT h/l after.
    ushort_t* yh = base, *yl = base + 8388608;
    ushort_t* wouth = base + 16777216, *woutl = base + 18874368;

    dim3 blk(256);

    split_plain4<<<dim3(4096), blk, 0, stream>>>(x, xh, xl, 1048576);
    split_transpose<<<dim3(128, 32), blk, 0, stream>>>(W_in, winh, winl, 1024, 4096);
    split_transpose<<<dim3(32, 64), blk, 0, stream>>>(W_out, wouth, woutl, 2048, 1024);

    // 1) xr = x @ W_in   (4096 x 4096 x 1024)
    gemm_mfma3<<<dim3(32, 32), blk, 0, stream>>>(xh, xl, winh, winl, xr, 4096, 4096, 1024);
    // 2) xs = silu(dwconv(xr[:, :2048]) + b_conv)
    conv_silu_k<<<dim3(4096), blk, 0, stream>>>(xr, W_conv, b_conv, xs, 8388608);
    // 3) xdbl = xs @ W_x  (4096 x 96 x 2048)
    gemm_f32<<<dim3(2, 64), blk, 0, stream>>>(xs, W_x, xdbl, 4096, 96, 2048,
                                              2048, 96, 96, nullptr, 0);
    // 4) delta = softplus(xdbl[:, :64] @ W_dt + b_dt)  (4096 x 2048 x 64)
    gemm_f32<<<dim3(32, 64), blk, 0, stream>>>(xdbl, W_dt, delta, 4096, 2048, 64,
                                               96, 2048, 2048, b_dt, 1);
    // 5) chunked scan (NC=64, CL=32)
    scan_p1<<<dim3(1024), blk, 0, stream>>>(delta, xs, xdbl, A_log, S, sumdt);
    scan_p2<<<dim3(256), blk, 0, stream>>>(S, sumdt, A_log);
    scan_p3<<<dim3(1024), blk, 0, stream>>>(delta, xs, xdbl, xr, A_log, Dp, S, yh, yl);
    // 6) out = y @ W_out  (4096 x 1024 x 2048)
    gemm_mfma3<<<dim3(8, 32), blk, 0, stream>>>(yh, yl, wouth, woutl, out, 4096, 1024, 2048);
}

// Round 4
// 538.556 us; speedup vs baseline: 2.8603x; 1.2565x over previous
//
#include <hip/hip_runtime.h>

// Shapes: b=2, L=2048, d_model=1024, d_inner=2048, d_state=16, dt_rank=64, d_conv=4
// bf16x3 MFMA for in-proj, out-proj, and (split-K) x_dbl GEMMs; fp32 tile GEMM
// for the K=64 delta GEMM; chunked 3-pass selective scan with n-in-registers.

typedef unsigned short ushort_t;
using short8 = __attribute__((ext_vector_type(8))) short;
using f32x4  = __attribute__((ext_vector_type(4))) float;
using gptr_t = const __attribute__((address_space(1))) unsigned short*;
using sptr_t = __attribute__((address_space(3))) unsigned short*;

#define NC 64   // chunks
#define CL 32   // chunk length  (NC*CL == 2048)

__device__ inline ushort_t f2bf(float v) {
    unsigned u = __float_as_uint(v);
    unsigned r = (u + 0x7fff + ((u >> 16) & 1)) >> 16;   // RNE
    return (ushort_t)r;
}
__device__ inline float bf2f(ushort_t h) { return __uint_as_float(((unsigned)h) << 16); }
__device__ inline void split2(float v, ushort_t& h, ushort_t& l) {
    h = f2bf(v);
    l = f2bf(v - bf2f(h));
}

// ---------------- converters ----------------

__global__ void split_plain4(const float* __restrict__ in, ushort_t* __restrict__ h,
                             ushort_t* __restrict__ l, int n4) {
    int i = blockIdx.x * blockDim.x + threadIdx.x;
    if (i >= n4) return;
    float4 v = ((const float4*)in)[i];
    ushort4 hh, ll;
    split2(v.x, hh.x, ll.x); split2(v.y, hh.y, ll.y);
    split2(v.z, hh.z, ll.z); split2(v.w, hh.w, ll.w);
    ((ushort4*)h)[i] = hh;
    ((ushort4*)l)[i] = ll;
}

// W: K x N fp32 -> Th/Tl: Npad x K bf16 (row-major), rows N..Npad-1 zeroed.
__global__ __launch_bounds__(256) void split_transpose(
    const float* __restrict__ W, ushort_t* __restrict__ Th, ushort_t* __restrict__ Tl,
    int K, int N) {
    __shared__ float tile[32][33];
    int n0 = blockIdx.x * 32, k0 = blockIdx.y * 32;
    int tx = threadIdx.x & 31, ty = threadIdx.x >> 5;
    #pragma unroll
    for (int j = 0; j < 4; ++j) {
        int k = ty + j * 8;
        tile[k][tx] = (n0 + tx < N) ? W[(size_t)(k0 + k) * N + n0 + tx] : 0.f;
    }
    __syncthreads();
    #pragma unroll
    for (int j = 0; j < 4; ++j) {
        int nrow = ty + j * 8;
        float v = tile[tx][nrow];
        ushort_t h, l;
        split2(v, h, l);
        size_t o = (size_t)(n0 + nrow) * K + k0 + tx;
        Th[o] = h; Tl[o] = l;
    }
}

// ---------------- bf16x3 MFMA GEMM ----------------
// C[M,N] = (Ah+Al)[M,K] @ (Bh+Bl)[K,N], B TRANSPOSED (N x K). Drop Al@Bl.
// Tile 128x128, BK=32, 4 waves (2x2), each wave 64x64.
__global__ __launch_bounds__(256) void gemm_mfma3(
    const ushort_t* __restrict__ Ah, const ushort_t* __restrict__ Al,
    const ushort_t* __restrict__ Bh, const ushort_t* __restrict__ Bl,
    float* __restrict__ C, int M, int N, int K) {
    __shared__ ushort_t sAh[4096], sAl[4096], sBh[4096], sBl[4096];
    const int tid  = threadIdx.x;
    const int wid  = tid >> 6;
    const int lane = tid & 63;
    const int bm = blockIdx.y * 128;
    const int bn = blockIdx.x * 128;
    const int wr = wid >> 1, wc = wid & 1;

    f32x4 acc[4][4];
    #pragma unroll
    for (int i = 0; i < 4; ++i)
        #pragma unroll
        for (int j = 0; j < 4; ++j) acc[i][j] = (f32x4){0.f, 0.f, 0.f, 0.f};

    for (int k0 = 0; k0 < K; k0 += 32) {
        #pragma unroll
        for (int issue = 0; issue < 2; ++issue) {
            const int off = wid * 2048 + issue * 1024 + lane * 16;
            const int row = off >> 6;
            const int ce  = (off & 63) >> 1;
            const size_t ga = (size_t)(bm + row) * K + k0 + ce;
            const size_t gb = (size_t)(bn + row) * K + k0 + ce;
            const int lo = (wid * 2048 + issue * 1024) >> 1;
            __builtin_amdgcn_global_load_lds((gptr_t)(Ah + ga), (sptr_t)&sAh[lo], 16, 0, 0);
            __builtin_amdgcn_global_load_lds((gptr_t)(Al + ga), (sptr_t)&sAl[lo], 16, 0, 0);
            __builtin_amdgcn_global_load_lds((gptr_t)(Bh + gb), (sptr_t)&sBh[lo], 16, 0, 0);
            __builtin_amdgcn_global_load_lds((gptr_t)(Bl + gb), (sptr_t)&sBl[lo], 16, 0, 0);
        }
        __syncthreads();

        const int fr = lane & 15;
        const int kb = (lane >> 4) * 8;
        short8 ah[4], al[4], bh[4], bl[4];
        #pragma unroll
        for (int i = 0; i < 4; ++i) {
            const int ra = (wr * 64 + i * 16 + fr) * 32 + kb;
            ah[i] = *(const short8*)&sAh[ra];
            al[i] = *(const short8*)&sAl[ra];
            const int rb = (wc * 64 + i * 16 + fr) * 32 + kb;
            bh[i] = *(const short8*)&sBh[rb];
            bl[i] = *(const short8*)&sBl[rb];
        }
        #pragma unroll
        for (int i = 0; i < 4; ++i)
            #pragma unroll
            for (int j = 0; j < 4; ++j) {
                acc[i][j] = __builtin_amdgcn_mfma_f32_16x16x32_bf16(ah[i], bh[j], acc[i][j], 0, 0, 0);
                acc[i][j] = __builtin_amdgcn_mfma_f32_16x16x32_bf16(ah[i], bl[j], acc[i][j], 0, 0, 0);
                acc[i][j] = __builtin_amdgcn_mfma_f32_16x16x32_bf16(al[i], bh[j], acc[i][j], 0, 0, 0);
            }
        __syncthreads();
    }

    #pragma unroll
    for (int i = 0; i < 4; ++i) {
        int row = bm + wr * 64 + i * 16 + (lane >> 4) * 4;
        #pragma unroll
        for (int j = 0; j < 4; ++j) {
            int col = bn + wc * 64 + j * 16 + (lane & 15);
            float* cp = C + (size_t)row * N + col;
            #pragma unroll
            for (int r = 0; r < 4; ++r) cp[(size_t)r * N] = acc[i][j][r];
        }
    }
}

// Split-K variant for xdbl = xs @ W_x (M=4096, Npad=128, K=2048).
// grid = (KSLICES=8, 32 M-tiles); each block does 128x128 x 256-K-chunk into
// partial[slice]. B = padded W_x^T (128 x 2048).
__global__ __launch_bounds__(256) void gemm_mfma3_sk(
    const ushort_t* __restrict__ Ah, const ushort_t* __restrict__ Al,
    const ushort_t* __restrict__ Bh, const ushort_t* __restrict__ Bl,
    float* __restrict__ partial, int K) {
    __shared__ ushort_t sAh[4096], sAl[4096], sBh[4096], sBl[4096];
    const int tid  = threadIdx.x;
    const int wid  = tid >> 6;
    const int lane = tid & 63;
    const int kslice = blockIdx.x;
    const int bm = blockIdx.y * 128;
    const int wr = wid >> 1, wc = wid & 1;
    const int kbeg = kslice * 256;

    f32x4 acc[4][4];
    #pragma unroll
    for (int i = 0; i < 4; ++i)
        #pragma unroll
        for (int j = 0; j < 4; ++j) acc[i][j] = (f32x4){0.f, 0.f, 0.f, 0.f};

    for (int k0 = kbeg; k0 < kbeg + 256; k0 += 32) {
        #pragma unroll
        for (int issue = 0; issue < 2; ++issue) {
            const int off = wid * 2048 + issue * 1024 + lane * 16;
            const int row = off >> 6;
            const int ce  = (off & 63) >> 1;
            const size_t ga = (size_t)(bm + row) * K + k0 + ce;
            const size_t gb = (size_t)row * K + k0 + ce;
            const int lo = (wid * 2048 + issue * 1024) >> 1;
            __builtin_amdgcn_global_load_lds((gptr_t)(Ah + ga), (sptr_t)&sAh[lo], 16, 0, 0);
            __builtin_amdgcn_global_load_lds((gptr_t)(Al + ga), (sptr_t)&sAl[lo], 16, 0, 0);
            __builtin_amdgcn_global_load_lds((gptr_t)(Bh + gb), (sptr_t)&sBh[lo], 16, 0, 0);
            __builtin_amdgcn_global_load_lds((gptr_t)(Bl + gb), (sptr_t)&sBl[lo], 16, 0, 0);
        }
        __syncthreads();

        const int fr = lane & 15;
        const int kb = (lane >> 4) * 8;
        short8 ah[4], al[4], bh[4], bl[4];
        #pragma unroll
        for (int i = 0; i < 4; ++i) {
            const int ra = (wr * 64 + i * 16 + fr) * 32 + kb;
            ah[i] = *(const short8*)&sAh[ra];
            al[i] = *(const short8*)&sAl[ra];
            const int rb = (wc * 64 + i * 16 + fr) * 32 + kb;
            bh[i] = *(const short8*)&sBh[rb];
            bl[i] = *(const short8*)&sBl[rb];
        }
        #pragma unroll
        for (int i = 0; i < 4; ++i)
            #pragma unroll
            for (int j = 0; j < 4; ++j) {
                acc[i][j] = __builtin_amdgcn_mfma_f32_16x16x32_bf16(ah[i], bh[j], acc[i][j], 0, 0, 0);
                acc[i][j] = __builtin_amdgcn_mfma_f32_16x16x32_bf16(ah[i], bl[j], acc[i][j], 0, 0, 0);
                acc[i][j] = __builtin_amdgcn_mfma_f32_16x16x32_bf16(al[i], bh[j], acc[i][j], 0, 0, 0);
            }
        __syncthreads();
    }

    float* Cp = partial + (size_t)kslice * 4096 * 128;
    #pragma unroll
    for (int i = 0; i < 4; ++i) {
        int row = bm + wr * 64 + i * 16 + (lane >> 4) * 4;
        #pragma unroll
        for (int j = 0; j < 4; ++j) {
            int col = wc * 64 + j * 16 + (lane & 15);
            float* cp = Cp + (size_t)row * 128 + col;
            #pragma unroll
            for (int r = 0; r < 4; ++r) cp[(size_t)r * 128] = acc[i][j][r];
        }
    }
}

// xdbl[i] = sum over 8 K-slices of partial. 131072 float4s.
__global__ void reduce8(const float4* __restrict__ p, float4* __restrict__ outp) {
    int i = blockIdx.x * 256 + threadIdx.x;
    float4 s = p[i];
    #pragma unroll
    for (int k = 1; k < 8; ++k) {
        float4 v = p[i + k * 131072];
        s.x += v.x; s.y += v.y; s.z += v.z; s.w += v.w;
    }
    outp[i] = s;
}

// ---------------- fp32 tile GEMM (delta GEMM) ----------------
#define BM 64
#define BN 64
#define BKK 16
__global__ __launch_bounds__(256) void gemm_f32(
    const float* __restrict__ A, const float* __restrict__ B, float* __restrict__ C,
    int M, int N, int K, int lda, int ldb, int ldc,
    const float* __restrict__ bias, int epi) {
    __shared__ float As[BKK][BM];
    __shared__ float Bs[BKK][BN];
    const int bm = blockIdx.y * BM;
    const int bn = blockIdx.x * BN;
    const int tid = threadIdx.x;
    const int tx = tid & 15;
    const int ty = tid >> 4;
    const int a_row = tid >> 2;
    const int a_col = (tid & 3) * 4;
    const int b_row = tid >> 4;
    const int b_col = (tid & 15) * 4;
    const bool fullN = (bn + BN <= N);

    float acc[4][4] = {};
    for (int k0 = 0; k0 < K; k0 += BKK) {
        {
            const float* ap = A + (size_t)(bm + a_row) * lda + (k0 + a_col);
            float4 av = *(const float4*)ap;
            As[a_col + 0][a_row] = av.x; As[a_col + 1][a_row] = av.y;
            As[a_col + 2][a_row] = av.z; As[a_col + 3][a_row] = av.w;
        }
        {
            const float* bp = B + (size_t)(k0 + b_row) * ldb + (bn + b_col);
            float4 bv;
            if (fullN) bv = *(const float4*)bp;
            else {
                bv.x = bv.y = bv.z = bv.w = 0.f;
                int rem = N - (bn + b_col);
                if (rem > 0) bv.x = bp[0];
                if (rem > 1) bv.y = bp[1];
                if (rem > 2) bv.z = bp[2];
                if (rem > 3) bv.w = bp[3];
            }
            Bs[b_row][b_col + 0] = bv.x; Bs[b_row][b_col + 1] = bv.y;
            Bs[b_row][b_col + 2] = bv.z; Bs[b_row][b_col + 3] = bv.w;
        }
        __syncthreads();
        #pragma unroll
        for (int k = 0; k < BKK; ++k) {
            float a[4], b[4];
            #pragma unroll
            for (int i = 0; i < 4; ++i) a[i] = As[k][ty * 4 + i];
            #pragma unroll
            for (int j = 0; j < 4; ++j) b[j] = Bs[k][tx * 4 + j];
            #pragma unroll
            for (int i = 0; i < 4; ++i)
                #pragma unroll
                for (int j = 0; j < 4; ++j)
                    acc[i][j] = fmaf(a[i], b[j], acc[i][j]);
        }
        __syncthreads();
    }
    #pragma unroll
    for (int i = 0; i < 4; ++i) {
        int r = bm + ty * 4 + i;
        #pragma unroll
        for (int j = 0; j < 4; ++j) {
            int col = bn + tx * 4 + j;
            if (col < N) {
                float v = acc[i][j];
                if (epi == 1) {
                    v += bias[col];
                    v = (v > 20.f) ? v : log1pf(__expf(v));
                }
                C[(size_t)r * ldc + col] = v;
            }
        }
    }
}

// ---------------- conv + silu (also emits xs as bf16 hi/lo) ----------------
__global__ void conv_silu_k(const float* __restrict__ xr, const float* __restrict__ Wc,
                            const float* __restrict__ bc, float* __restrict__ xs,
                            ushort_t* __restrict__ xsh, ushort_t* __restrict__ xsl,
                            int total) {
    for (int idx = blockIdx.x * blockDim.x + threadIdx.x; idx < total;
         idx += gridDim.x * blockDim.x) {
        int d = idx & 2047;
        int l = (idx >> 11) & 2047;
        int b = idx >> 22;
        float acc = bc[d];
        const float* wp = Wc + d * 4;
        #pragma unroll
        for (int k = 0; k < 4; ++k) {
            int ll = l - 3 + k;
            if (ll >= 0)
                acc = fmaf(xr[((size_t)(b * 2048 + ll) << 12) + d], wp[k], acc);
        }
        float v = acc / (1.f + __expf(-acc));
        xs[idx] = v;
        ushort_t h, lo;
        split2(v, h, lo);
        xsh[idx] = h;
        xsl[idx] = lo;
    }
}

// ---------------- chunked selective scan, n in registers ----------------
// xdbl row stride = 128 floats (cols 0..63 dt_in, 64..79 B, 80..95 C).

__global__ __launch_bounds__(256) void scan_p1(
    const float* __restrict__ delta, const float* __restrict__ xs,
    const float* __restrict__ xdbl, const float* __restrict__ A_log,
    float* __restrict__ S, float* __restrict__ sumdt) {
    const int u = blockIdx.x * 256 + threadIdx.x;
    const int chunk = u >> 12;
    const int c = u & 4095;
    const int b = c >> 11, d = c & 2047;

    float a[16];
    #pragma unroll
    for (int i = 0; i < 4; ++i) {
        float4 v = ((const float4*)(A_log + d * 16))[i];
        a[4 * i + 0] = -__expf(v.x); a[4 * i + 1] = -__expf(v.y);
        a[4 * i + 2] = -__expf(v.z); a[4 * i + 3] = -__expf(v.w);
    }
    float h[16];
    #pragma unroll
    for (int n = 0; n < 16; ++n) h[n] = 0.f;
    float sdt = 0.f;

    const size_t row0 = (size_t)b * 2048 + (size_t)chunk * CL;
    const float4* xd4 = (const float4*)xdbl;
    #pragma unroll 2
    for (int t = 0; t < CL; ++t) {
        const size_t row = row0 + t;
        float dt = delta[row * 2048 + d];
        float xv = xs[row * 2048 + d];
        float4 Bv[4];
        #pragma unroll
        for (int i = 0; i < 4; ++i) Bv[i] = xd4[row * 32 + 16 + i];
        const float* Bf = (const float*)Bv;
        sdt += dt;
        float du = dt * xv;
        #pragma unroll
        for (int n = 0; n < 16; ++n) {
            float dA = __expf(dt * a[n]);
            h[n] = fmaf(dA, h[n], du * Bf[n]);
        }
    }
    float4* S4 = (float4*)(S + ((size_t)chunk * 4096 + c) * 16);
    #pragma unroll
    for (int i = 0; i < 4; ++i)
        S4[i] = make_float4(h[4 * i + 0], h[4 * i + 1], h[4 * i + 2], h[4 * i + 3]);
    sumdt[chunk * 4096 + c] = sdt;
}

__global__ __launch_bounds__(256) void scan_p2(
    float* __restrict__ S, const float* __restrict__ sumdt,
    const float* __restrict__ A_log) {
    const int idx = blockIdx.x * blockDim.x + threadIdx.x;
    const int n = idx & 15;
    const int c = (idx >> 4) & 4095;
    const int d = c & 2047;
    const float a = -__expf(A_log[d * 16 + n]);
    float h = 0.f;
    for (int k = 0; k < NC; ++k) {
        const size_t o = ((size_t)k * 4096 + c) * 16 + n;
        float carry = S[o];
        S[o] = h;
        float P = __expf(a * sumdt[k * 4096 + c]);
        h = fmaf(P, h, carry);
    }
}

__global__ __launch_bounds__(256) void scan_p3(
    const float* __restrict__ delta, const float* __restrict__ xs,
    const float* __restrict__ xdbl, const float* __restrict__ xr,
    const float* __restrict__ A_log, const float* __restrict__ Dp,
    const float* __restrict__ H0,
    ushort_t* __restrict__ yh, ushort_t* __restrict__ yl) {
    const int u = blockIdx.x * 256 + threadIdx.x;
    const int chunk = u >> 12;
    const int c = u & 4095;
    const int b = c >> 11, d = c & 2047;

    float a[16];
    #pragma unroll
    for (int i = 0; i < 4; ++i) {
        float4 v = ((const float4*)(A_log + d * 16))[i];
        a[4 * i + 0] = -__expf(v.x); a[4 * i + 1] = -__expf(v.y);
        a[4 * i + 2] = -__expf(v.z); a[4 * i + 3] = -__expf(v.w);
    }
    float h[16];
    const float4* H4 = (const float4*)(H0 + ((size_t)chunk * 4096 + c) * 16);
    #pragma unroll
    for (int i = 0; i < 4; ++i) {
        float4 v = H4[i];
        h[4 * i + 0] = v.x; h[4 * i + 1] = v.y; h[4 * i + 2] = v.z; h[4 * i + 3] = v.w;
    }
    const float Dd = Dp[d];

    const size_t row0 = (size_t)b * 2048 + (size_t)chunk * CL;
    const float4* xd4 = (const float4*)xdbl;
    #pragma unroll 2
    for (int t = 0; t < CL; ++t) {
        const size_t row = row0 + t;
        float dt = delta[row * 2048 + d];
        float xv = xs[row * 2048 + d];
        float4 BC[8];
        #pragma unroll
        for (int i = 0; i < 8; ++i) BC[i] = xd4[row * 32 + 16 + i];
        const float* Bf = (const float*)BC;
        const float* Cf = Bf + 16;
        float du = dt * xv;
        float acc = 0.f;
        #pragma unroll
        for (int n = 0; n < 16; ++n) {
            float dA = __expf(dt * a[n]);
            h[n] = fmaf(dA, h[n], du * Bf[n]);
            acc = fmaf(h[n], Cf[n], acc);
        }
        float rv = xr[(row << 12) + 2048 + d];
        float yv = fmaf(Dd, xv, acc) * (rv / (1.f + __expf(-rv)));
        ushort_t hb, lb;
        split2(yv, hb, lb);
        yh[row * 2048 + d] = hb;
        yl[row * 2048 + d] = lb;
    }
}

// ---------------- launch ----------------
extern "C" void kernel_launch(void* const* d_in, const int* in_sizes, int n_in,
                              void* d_out, int out_size, void* d_ws, size_t ws_size,
                              hipStream_t stream) {
    const float* x      = (const float*)d_in[0];
    const float* W_in   = (const float*)d_in[1];
    const float* W_conv = (const float*)d_in[2];
    const float* b_conv = (const float*)d_in[3];
    const float* W_x    = (const float*)d_in[4];
    const float* W_dt   = (const float*)d_in[5];
    const float* b_dt   = (const float*)d_in[6];
    const float* A_log  = (const float*)d_in[7];
    const float* Dp     = (const float*)d_in[8];
    const float* W_out  = (const float*)d_in[9];
    float* out = (float*)d_out;

    float* ws    = (float*)d_ws;
    float* xr    = ws;                      // 16,777,216 f
    float* xs    = xr + 16777216;           //  8,388,608 f
    float* xdbl  = xs + 8388608;            //    524,288 f (4096 x 128)
    float* delta = xdbl + 524288;           //  8,388,608 f
    float* S     = delta + 8388608;         //  4,194,304 f
    float* sumdt = S + 4194304;             //    262,144 f
    ushort_t* base = (ushort_t*)(sumdt + 262144);
    // phase A: xh/xl (4096x1024), WinT h/l (4096x1024) -- dead after in-GEMM
    ushort_t* xh = base, *xl = base + 4194304;
    ushort_t* winh = base + 8388608, *winl = base + 12582912;
    // persistent: WoutT h/l (1024x2048), WxT h/l (128x2048 padded)
    ushort_t* wouth = base + 16777216, *woutl = base + 18874368;
    ushort_t* wxh = base + 20971520, *wxl = base + 21233664;
    // xs bf16 (4096x2048 each)
    ushort_t* xsh = base + 21495808, *xsl = base + 29884416;
    // phase B: yh/yl overlap phase A region; partial overlaps xh/xl (as float)
    ushort_t* yh = base, *yl = base + 8388608;
    float* partial = (float*)base;          // 8 x 4096 x 128 f = 16.8 MB

    dim3 blk(256);

    split_plain4<<<dim3(4096), blk, 0, stream>>>(x, xh, xl, 1048576);
    split_transpose<<<dim3(128, 32), blk, 0, stream>>>(W_in, winh, winl, 1024, 4096);
    split_transpose<<<dim3(32, 64), blk, 0, stream>>>(W_out, wouth, woutl, 2048, 1024);
    split_transpose<<<dim3(4, 64), blk, 0, stream>>>(W_x, wxh, wxl, 2048, 96);  // pad N->128

    // 1) xr = x @ W_in   (4096 x 4096 x 1024)
    gemm_mfma3<<<dim3(32, 32), blk, 0, stream>>>(xh, xl, winh, winl, xr, 4096, 4096, 1024);
    // 2) xs = silu(dwconv(xr[:, :2048]) + b_conv)  (+ bf16 split)
    conv_silu_k<<<dim3(4096), blk, 0, stream>>>(xr, W_conv, b_conv, xs, xsh, xsl, 8388608);
    // 3) xdbl = xs @ W_x  (4096 x 128pad x 2048), split-K=8 MFMA + reduce
    gemm_mfma3_sk<<<dim3(8, 32), blk, 0, stream>>>(xsh, xsl, wxh, wxl, partial, 2048);
    reduce8<<<dim3(512), blk, 0, stream>>>((const float4*)partial, (float4*)xdbl);
    // 4) delta = softplus(xdbl[:, :64] @ W_dt + b_dt)  (4096 x 2048 x 64)
    gemm_f32<<<dim3(32, 64), blk, 0, stream>>>(xdbl, W_dt, delta, 4096, 2048, 64,
                                               128, 2048, 2048, b_dt, 1);
    // 5) chunked scan (NC=64, CL=32)
    scan_p1<<<dim3(1024), blk, 0, stream>>>(delta, xs, xdbl, A_log, S, sumdt);
    scan_p2<<<dim3(256), blk, 0, stream>>>(S, sumdt, A_log);
    scan_p3<<<dim3(1024), blk, 0, stream>>>(delta, xs, xdbl, xr, A_log, Dp, S, yh, yl);
    // 6) out = y @ W_out  (4096 x 1024 x 2048)
    gemm_mfma3<<<dim3(8, 32), blk, 0, stream>>>(yh, yl, wouth, woutl, out, 4096, 1024, 2048);
}